// Round 16
// baseline (230.471 us; speedup 1.0000x reference)
//
#include <hip/hip_runtime.h>
#include <hip/hip_fp16.h>

#define NN 100000
#define NE 1600000
#define NG 512
#define OUTS 8128
#define NB2 196     // coarse buckets of 512 nodes (196*512 = 100352 >= NN)
#define CHUNK 8192
#define NPB 196     // ceil(NE/CHUNK)

typedef short bf16x8 __attribute__((ext_vector_type(8)));
typedef _Float16 f16x8 __attribute__((ext_vector_type(8)));
typedef _Float16 f16x2 __attribute__((ext_vector_type(2)));
typedef float f32x4 __attribute__((ext_vector_type(4)));

__device__ __forceinline__ unsigned pack_bf16x2(float a, float b) {
    unsigned ua = __float_as_uint(a);
    unsigned ub = __float_as_uint(b);
    ua = (ua + 0x7fffu + ((ua >> 16) & 1u)) >> 16;
    ub = (ub + 0x7fffu + ((ub >> 16) & 1u)) >> 16;
    return ua | (ub << 16);
}
__device__ __forceinline__ unsigned short f2bf(float f) {
    unsigned u = __float_as_uint(f);
    u = (u + 0x7fffu + ((u >> 16) & 1u)) >> 16;
    return (unsigned short)u;
}
// f32 pair -> packed f16x2 (RTZ), as raw uint
__device__ __forceinline__ unsigned cvt_pkrtz_u(float a, float b) {
    auto h = __builtin_amdgcn_cvt_pkrtz(a, b);
    union { decltype(h) h2; unsigned u; } c; c.h2 = h; return c.u;
}
__device__ __forceinline__ f16x2 u2h(unsigned u) { union { unsigned u; f16x2 h; } c; c.u = u; return c.h; }

// e4m3 encode, f >= 0 (relu'd): e4m3(v) == f16(v/256) with 10->3 mantissa round
__device__ __forceinline__ unsigned f2fp8(float f) {
    unsigned h = (unsigned)__half_as_ushort(__float2half(f * 0.00390625f));
    return (h + 0x3Fu + ((h >> 7) & 1u)) >> 7;
}
// e4m3 encode, signed
__device__ __forceinline__ unsigned f2fp8s(float f) {
    unsigned h = (unsigned)__half_as_ushort(__float2half(f * 0.00390625f));
    unsigned s = (h >> 8) & 0x80u;
    unsigned mag = h & 0x7fffu;
    return s | ((mag + 0x3Fu + ((mag >> 7) & 1u)) >> 7);
}

// unsigned packed decode (relu'd data): 4 fp8 -> two f16x2 accumulators
#define DECO(W, LO, HI) { LO += u2h(((W) & 0x007f007fu) << 7); HI += u2h(((W) & 0x7f007f00u) >> 1); }
// signed packed decode
#define DECOS(W, LO, HI) { \
    LO += u2h((((W) & 0x007f007fu) << 7) | (((W) & 0x00800080u) << 8)); \
    HI += u2h((((W) & 0x7f007f00u) >> 1) | ((W) & 0x80008000u)); }

// ---- phase 1 + weight conversions in one launch ----
__global__ __launch_bounds__(512) void k_part(const int* __restrict__ src, const int* __restrict__ dst,
        int* __restrict__ tmp, int* __restrict__ scanhist,
        const float* __restrict__ W1, const float* __restrict__ W2, const float* __restrict__ D3,
        unsigned short* __restrict__ wt1, unsigned short* __restrict__ wt2,
        unsigned short* __restrict__ wt3t) {
    int t = threadIdx.x;
    if (blockIdx.x >= NPB) {
        int blk2 = blockIdx.x - NPB;
        if (blk2 < 48) {
            int i = blk2 * 512 + t;
            if (i < 8192) {                      // wt1: [128][64] f16, transposed
                int n = i >> 6, k = i & 63;
                wt1[i] = (unsigned short)__half_as_ushort(__float2half(W1[k * 128 + n]));
            } else {                             // wt2: [128][128] bf16, transposed
                int e = i - 8192;
                int n = e >> 7, k = e & 127;
                wt2[e] = f2bf(W2[k * 128 + n]);
            }
        } else {
            __shared__ float tile[32][33];
            int bb = blk2 - 48;                  // 0..1015
            int n0 = (bb % 254) * 32, k0 = (bb / 254) * 32;
            for (int i = t; i < 1024; i += 512) {
                int kk = i >> 5, nn = i & 31;
                tile[kk][nn] = D3[(long)(k0 + kk) * OUTS + n0 + nn];
            }
            __syncthreads();
            for (int i = t; i < 1024; i += 512) {
                int nn = i >> 5, kk = i & 31;
                wt3t[(long)(n0 + nn) * 128 + k0 + kk] =
                    (unsigned short)__half_as_ushort(__float2half(tile[kk][nn]));
            }
        }
        return;
    }
    __shared__ int hist[NB2], cur[NB2], scan[256];
    int p = blockIdx.x;
    int e0 = p * CHUNK;
    int e1 = min(e0 + CHUNK, NE);
    for (int i = t; i < NB2; i += 512) hist[i] = 0;
    __syncthreads();
    for (int e = e0 + t; e < e1; e += 512)
        atomicAdd(&hist[dst[e] >> 9], 1);
    __syncthreads();
    int h = 0;
    if (t < 256) { h = (t < NB2) ? hist[t] : 0; scan[t] = h; }
    __syncthreads();
    for (int off = 1; off < 256; off <<= 1) {
        int v = (t < 256 && t >= off) ? scan[t - off] : 0;
        __syncthreads();
        if (t < 256) scan[t] += v;
        __syncthreads();
    }
    if (t < NB2) {
        int excl = scan[t] - h;
        cur[t] = excl;
        scanhist[p * (NB2 + 1) + t] = excl;
    }
    if (t == 0) scanhist[p * (NB2 + 1) + NB2] = e1 - e0;
    __syncthreads();
    for (int e = e0 + t; e < e1; e += 512) {
        int d = dst[e];
        int b = d >> 9;
        int r = atomicAdd(&cur[b], 1);          // LDS atomic only
        tmp[e0 + r] = (src[e] << 9) | (d & 511);
    }
}

// ---- block 0: bucket totals + scan -> bucketbase; blocks 1..: segment ends ----
__global__ __launch_bounds__(256) void k_btotseg(const int* __restrict__ scanhist,
        int* __restrict__ bucketbase, const int* __restrict__ batch, int* __restrict__ seg_end) {
    if (blockIdx.x == 0) {
        __shared__ int sc[256];
        int b = threadIdx.x;
        int tot = 0;
        if (b < NB2) {
            for (int p = 0; p < NPB; ++p)
                tot += scanhist[p * (NB2 + 1) + b + 1] - scanhist[p * (NB2 + 1) + b];
        }
        sc[b] = tot;
        __syncthreads();
        for (int off = 1; off < 256; off <<= 1) {
            int v = (b >= off) ? sc[b - off] : 0;
            __syncthreads();
            sc[b] += v;
            __syncthreads();
        }
        if (b < NB2) bucketbase[b] = sc[b] - tot;
    } else {
        int i = (blockIdx.x - 1) * 256 + threadIdx.x;
        if (i >= NN) return;
        int b = batch[i];
        int bn = (i == NN - 1) ? NG : batch[i + 1];
        for (int g = b; g < bn; ++g) seg_end[g] = i + 1;
        if (i == 0) {
            for (int g = 0; g < b; ++g) seg_end[g] = 0;
        }
    }
}

// ---- phase 2: per-bucket count+scan+place; emits cnti/rowptr/dinv/colidx AND u1b = fp8(x*dinv) ----
__global__ __launch_bounds__(1024) void k_fill2(const int* __restrict__ bucketbase,
        const int* __restrict__ scanhist, const int* __restrict__ tmp,
        int* __restrict__ colidx, int* __restrict__ cnti, int* __restrict__ rowptr,
        float* __restrict__ dinv, const float* __restrict__ x, unsigned* __restrict__ u1b) {
    __shared__ int lc[512], rb[512], sc[256];
    __shared__ float ldv[512];
    int b = blockIdx.x, t = threadIdx.x;
    int n0 = b << 9;
    if (t < 512) lc[t] = 0;
    __syncthreads();
    int w = t >> 6, lane = t & 63;              // w in 0..15
    for (int p = w; p < NPB; p += 16) {
        int s0 = scanhist[p * (NB2 + 1) + b];
        int s1 = scanhist[p * (NB2 + 1) + b + 1];
        int base = p * CHUNK;
        for (int i = s0 + lane; i < s1; i += 64)
            atomicAdd(&lc[tmp[base + i] & 511], 1);
    }
    __syncthreads();
    int v0 = 0, v1 = 0, s = 0;
    if (t < 256) { v0 = lc[2 * t]; v1 = lc[2 * t + 1]; s = v0 + v1; sc[t] = s; }
    __syncthreads();
    for (int off = 1; off < 256; off <<= 1) {
        int xv = (t < 256 && t >= off) ? sc[t - off] : 0;
        __syncthreads();
        if (t < 256) sc[t] += xv;
        __syncthreads();
    }
    if (t < 256) {
        int excl = sc[t] - s;
        int base0 = bucketbase[b];
        rb[2 * t] = base0 + excl;
        rb[2 * t + 1] = base0 + excl + v0;
        float dv0 = rsqrtf((float)v0 + 1.0f);
        float dv1 = rsqrtf((float)v1 + 1.0f);
        ldv[2 * t] = dv0;
        ldv[2 * t + 1] = dv1;
        int node0 = n0 + 2 * t;
        if (node0 < NN) {
            cnti[node0] = v0;
            rowptr[node0] = base0 + excl;
            dinv[node0] = dv0;
        }
        if (node0 + 1 < NN) {
            cnti[node0 + 1] = v1;
            rowptr[node0 + 1] = base0 + excl + v0;
            dinv[node0 + 1] = dv1;
        }
    }
    __syncthreads();
    if (t < 512) lc[t] = 0;
    __syncthreads();
    for (int p = w; p < NPB; p += 16) {
        int s0 = scanhist[p * (NB2 + 1) + b];
        int s1 = scanhist[p * (NB2 + 1) + b + 1];
        int base = p * CHUNK;
        for (int i = s0 + lane; i < s1; i += 64) {
            int v = tmp[base + i];
            int dl = v & 511;
            int pos = atomicAdd(&lc[dl], 1);    // LDS atomic only
            colidx[rb[dl] + pos] = v >> 9;
        }
    }
    // x-scale phase: u1b[node][c] = fp8s(x*dinv), 16 uints (64ch) per node
    for (int i = t; i < 512 * 16; i += 1024) {
        int local = i >> 4, c = i & 15;
        int node = n0 + local;
        if (node >= NN) continue;
        float4 xv = *(const float4*)&x[(long)node * 64 + c * 4];
        float d = ldv[local];
        unsigned o = f2fp8s(xv.x * d) | (f2fp8s(xv.y * d) << 8)
                   | (f2fp8s(xv.z * d) << 16) | (f2fp8s(xv.w * d) << 24);
        u1b[node * 16 + c] = o;
    }
}

// ---- fused conv1: gather (signed fp8, 64ch) + f16 MFMA GEMM -> fp8 out ----
// 4 waves x 16 nodes; lane gathers its own A-fragment channels (ks*32 + kg*8 + j)
__global__ __launch_bounds__(256) void k_gconv1(const int* __restrict__ rowptr,
        const int* __restrict__ cnti, const int* __restrict__ colidx,
        const unsigned* __restrict__ u, const float* __restrict__ dinv,
        const unsigned short* __restrict__ wt, const float* __restrict__ bias,
        unsigned char* __restrict__ outp) {
    constexpr int K = 64, SLOTS = 8;
    __shared__ __align__(16) unsigned short wlds[128 * K];
    char* lb = (char*)wlds;
    for (int c = threadIdx.x; c < 128 * SLOTS; c += 256) {
        int n = c / SLOTS, s = c - n * SLOTS;
        *(uint4*)(lb + n * (2 * K) + ((s ^ (n & 7)) << 4)) = *(const uint4*)(wt + c * 8);
    }
    int lane = threadIdx.x & 63;
    int w = threadIdx.x >> 6;
    int r0 = blockIdx.x * 64 + w * 16;
    int node = r0 + (lane & 15);
    if (node >= NN) node = NN - 1;
    int kg = lane >> 4;                          // 0..3
    const uint2* uf = (const uint2*)u;           // row = 8 uint2 (64 fp8)
    f16x2 z = {(_Float16)0.f, (_Float16)0.f};
    f16x2 A0l = z, A0h = z, A1l = z, A1h = z;    // ks=0, channels kg*8..kg*8+7
    f16x2 B0l = z, B0h = z, B1l = z, B1h = z;    // ks=1
    f16x2 A0l2 = z, A0h2 = z, A1l2 = z, A1h2 = z;
    f16x2 B0l2 = z, B0h2 = z, B1l2 = z, B1h2 = z;
    {
        uint2 s0 = uf[node * 8 + kg];
        uint2 s1v = uf[node * 8 + 4 + kg];
        DECOS(s0.x, A0l, A0h) DECOS(s0.y, A1l, A1h)
        DECOS(s1v.x, B0l, B0h) DECOS(s1v.y, B1l, B1h)
    }
    int n = cnti[node];
    const int* ci = colidx + rowptr[node];
    int j = 0;
    for (; j + 2 <= n; j += 2) {
        int sa = ci[j], sb = ci[j + 1];
        uint2 a0 = uf[sa * 8 + kg];
        uint2 a1 = uf[sa * 8 + 4 + kg];
        uint2 b0 = uf[sb * 8 + kg];
        uint2 b1 = uf[sb * 8 + 4 + kg];
        DECOS(a0.x, A0l, A0h) DECOS(a0.y, A1l, A1h)
        DECOS(a1.x, B0l, B0h) DECOS(a1.y, B1l, B1h)
        DECOS(b0.x, A0l2, A0h2) DECOS(b0.y, A1l2, A1h2)
        DECOS(b1.x, B0l2, B0h2) DECOS(b1.y, B1l2, B1h2)
    }
    if (j < n) {
        int sa = ci[j];
        uint2 a0 = uf[sa * 8 + kg];
        uint2 a1 = uf[sa * 8 + 4 + kg];
        DECOS(a0.x, A0l, A0h) DECOS(a0.y, A1l, A1h)
        DECOS(a1.x, B0l, B0h) DECOS(a1.y, B1l, B1h)
    }
    A0l += A0l2; A0h += A0h2; A1l += A1l2; A1h += A1h2;
    B0l += B0l2; B0h += B0h2; B1l += B1l2; B1h += B1h2;
    float d = dinv[node] * 256.0f;
    union { uint4 u4; f16x8 h; } fa0, fa1;
    fa0.u4.x = cvt_pkrtz_u((float)A0l[0] * d, (float)A0h[0] * d);
    fa0.u4.y = cvt_pkrtz_u((float)A0l[1] * d, (float)A0h[1] * d);
    fa0.u4.z = cvt_pkrtz_u((float)A1l[0] * d, (float)A1h[0] * d);
    fa0.u4.w = cvt_pkrtz_u((float)A1l[1] * d, (float)A1h[1] * d);
    fa1.u4.x = cvt_pkrtz_u((float)B0l[0] * d, (float)B0h[0] * d);
    fa1.u4.y = cvt_pkrtz_u((float)B0l[1] * d, (float)B0h[1] * d);
    fa1.u4.z = cvt_pkrtz_u((float)B1l[0] * d, (float)B1h[0] * d);
    fa1.u4.w = cvt_pkrtz_u((float)B1l[1] * d, (float)B1h[1] * d);
    __syncthreads();
    f32x4 acc[8];
    #pragma unroll
    for (int t = 0; t < 8; ++t) acc[t] = (f32x4){0.f, 0.f, 0.f, 0.f};
    #pragma unroll
    for (int t = 0; t < 8; ++t) {
        int nn = t * 16 + (lane & 15);
        {
            union { bf16x8 r; f16x8 h; } cb;
            cb.r = *(const bf16x8*)(lb + nn * (2 * K) + (((0 * 4 + kg) ^ (nn & 7)) << 4));
            acc[t] = __builtin_amdgcn_mfma_f32_16x16x32_f16(fa0.h, cb.h, acc[t], 0, 0, 0);
        }
        {
            union { bf16x8 r; f16x8 h; } cb;
            cb.r = *(const bf16x8*)(lb + nn * (2 * K) + (((1 * 4 + kg) ^ (nn & 7)) << 4));
            acc[t] = __builtin_amdgcn_mfma_f32_16x16x32_f16(fa1.h, cb.h, acc[t], 0, 0, 0);
        }
    }
    float bv[8];
    #pragma unroll
    for (int t = 0; t < 8; ++t) bv[t] = bias[t * 16 + (lane & 15)];
    #pragma unroll
    for (int r = 0; r < 4; ++r) {
        long row = r0 + (lane >> 4) * 4 + r;
        if (row >= NN) continue;
        float dd = dinv[row];
        #pragma unroll
        for (int t = 0; t < 8; ++t) {
            float val = fmaxf(acc[t][r] + bv[t], 0.f);
            outp[row * 128 + t * 16 + (lane & 15)] = (unsigned char)f2fp8(val * (16.0f * dd));
        }
    }
}

// ---- fused conv2: gather (unsigned fp8, 128ch) + bf16 MFMA GEMM -> bf16 out ----
__global__ __launch_bounds__(256) void k_gconv2(const int* __restrict__ rowptr,
        const int* __restrict__ cnti, const int* __restrict__ colidx,
        const unsigned* __restrict__ u, const float* __restrict__ dinv,
        const unsigned short* __restrict__ wt, const float* __restrict__ bias,
        unsigned short* __restrict__ outp) {
    constexpr int K = 128, SLOTS = 16;
    __shared__ __align__(16) unsigned short wlds[128 * K];
    char* lb = (char*)wlds;
    for (int c = threadIdx.x; c < 128 * SLOTS; c += 256) {
        int n = c / SLOTS, s = c - n * SLOTS;
        *(uint4*)(lb + n * (2 * K) + ((s ^ (n & 7)) << 4)) = *(const uint4*)(wt + c * 8);
    }
    int lane = threadIdx.x & 63;
    int w = threadIdx.x >> 6;
    int r0 = blockIdx.x * 64 + w * 16;
    int node = r0 + (lane & 15);
    if (node >= NN) node = NN - 1;
    int kg = lane >> 4;
    const uint2* uf = (const uint2*)u;           // row = 16 uint2 (128 fp8)
    f16x2 z = {(_Float16)0.f, (_Float16)0.f};
    f16x2 L0[4], H0[4], L1[4], H1[4];            // per-ks: uint c (L0/H0) and c+1 (L1/H1)
    f16x2 L0s[4], H0s[4], L1s[4], H1s[4];        // shadow set
    #pragma unroll
    for (int ks = 0; ks < 4; ++ks) { L0[ks]=z; H0[ks]=z; L1[ks]=z; H1[ks]=z;
                                     L0s[ks]=z; H0s[ks]=z; L1s[ks]=z; H1s[ks]=z; }
    #pragma unroll
    for (int ks = 0; ks < 4; ++ks) {
        uint2 sv = uf[node * 16 + ks * 4 + kg];
        DECO(sv.x, L0[ks], H0[ks]) DECO(sv.y, L1[ks], H1[ks])
    }
    int n = cnti[node];
    const int* ci = colidx + rowptr[node];
    int j = 0;
    for (; j + 2 <= n; j += 2) {
        int sa = ci[j], sb = ci[j + 1];
        uint2 a0 = uf[sa * 16 + kg];
        uint2 a1 = uf[sa * 16 + 4 + kg];
        uint2 a2 = uf[sa * 16 + 8 + kg];
        uint2 a3 = uf[sa * 16 + 12 + kg];
        uint2 b0 = uf[sb * 16 + kg];
        uint2 b1 = uf[sb * 16 + 4 + kg];
        uint2 b2 = uf[sb * 16 + 8 + kg];
        uint2 b3 = uf[sb * 16 + 12 + kg];
        DECO(a0.x, L0[0], H0[0]) DECO(a0.y, L1[0], H1[0])
        DECO(a1.x, L0[1], H0[1]) DECO(a1.y, L1[1], H1[1])
        DECO(a2.x, L0[2], H0[2]) DECO(a2.y, L1[2], H1[2])
        DECO(a3.x, L0[3], H0[3]) DECO(a3.y, L1[3], H1[3])
        DECO(b0.x, L0s[0], H0s[0]) DECO(b0.y, L1s[0], H1s[0])
        DECO(b1.x, L0s[1], H0s[1]) DECO(b1.y, L1s[1], H1s[1])
        DECO(b2.x, L0s[2], H0s[2]) DECO(b2.y, L1s[2], H1s[2])
        DECO(b3.x, L0s[3], H0s[3]) DECO(b3.y, L1s[3], H1s[3])
    }
    if (j < n) {
        int sa = ci[j];
        #pragma unroll
        for (int ks = 0; ks < 4; ++ks) {
            uint2 av = uf[sa * 16 + ks * 4 + kg];
            DECO(av.x, L0[ks], H0[ks]) DECO(av.y, L1[ks], H1[ks])
        }
    }
    #pragma unroll
    for (int ks = 0; ks < 4; ++ks) {
        L0[ks] += L0s[ks]; H0[ks] += H0s[ks];
        L1[ks] += L1s[ks]; H1[ks] += H1s[ks];
    }
    float d = dinv[node] * 16.0f;
    union { uint4 u4; bf16x8 r; } fa[4];
    #pragma unroll
    for (int ks = 0; ks < 4; ++ks) {
        fa[ks].u4.x = pack_bf16x2((float)L0[ks][0] * d, (float)H0[ks][0] * d);
        fa[ks].u4.y = pack_bf16x2((float)L0[ks][1] * d, (float)H0[ks][1] * d);
        fa[ks].u4.z = pack_bf16x2((float)L1[ks][0] * d, (float)H1[ks][0] * d);
        fa[ks].u4.w = pack_bf16x2((float)L1[ks][1] * d, (float)H1[ks][1] * d);
    }
    __syncthreads();
    f32x4 acc[8];
    #pragma unroll
    for (int t = 0; t < 8; ++t) acc[t] = (f32x4){0.f, 0.f, 0.f, 0.f};
    #pragma unroll
    for (int ks = 0; ks < 4; ++ks) {
        #pragma unroll
        for (int t = 0; t < 8; ++t) {
            int nn = t * 16 + (lane & 15);
            int slot = ks * 4 + kg;
            bf16x8 braw = *(const bf16x8*)(lb + nn * (2 * K) + ((slot ^ (nn & 7)) << 4));
            acc[t] = __builtin_amdgcn_mfma_f32_16x16x32_bf16(fa[ks].r, braw, acc[t], 0, 0, 0);
        }
    }
    float bv[8];
    #pragma unroll
    for (int t = 0; t < 8; ++t) bv[t] = bias[t * 16 + (lane & 15)];
    #pragma unroll
    for (int r = 0; r < 4; ++r) {
        long row = r0 + (lane >> 4) * 4 + r;
        if (row >= NN) continue;
        #pragma unroll
        for (int t = 0; t < 8; ++t) {
            float val = fmaxf(acc[t][r] + bv[t], 0.f);
            outp[row * 128 + t * 16 + (lane & 15)] = f2bf(val);
        }
    }
}

// ---- fused: segmented mean pool + mu/lv/z + 2 MLP layers; one block (256 thr) per graph ----
__global__ __launch_bounds__(256) void k_pooldec(const unsigned* __restrict__ h,
        const int* __restrict__ seg_end,
        const float* __restrict__ Wmu, const float* __restrict__ bmu,
        const float* __restrict__ Wlv, const float* __restrict__ blv,
        const float* __restrict__ eps,
        const float* __restrict__ D1, const float* __restrict__ d1,
        const float* __restrict__ D2, const float* __restrict__ d2,
        float* __restrict__ mu_o, float* __restrict__ lv_o,
        unsigned short* __restrict__ p2out) {
    __shared__ float part[3][128];
    __shared__ float row[128], mlv[128], zr[64], p1[128];
    int g = blockIdx.x;
    int w = threadIdx.x >> 6, t64 = threadIdx.x & 63;
    int s = (g == 0) ? 0 : seg_end[g - 1];
    int e = seg_end[g];
    float a0 = 0.f, a1 = 0.f;
    for (int i = s + w; i < e; i += 4) {
        unsigned u = h[(long)i * 64 + t64];
        a0 += __uint_as_float(u << 16);
        a1 += __uint_as_float(u & 0xffff0000u);
    }
    if (w) { part[w - 1][t64 * 2] = a0; part[w - 1][t64 * 2 + 1] = a1; }
    __syncthreads();
    if (w == 0) {
        a0 += part[0][t64 * 2] + part[1][t64 * 2] + part[2][t64 * 2];
        a1 += part[0][t64 * 2 + 1] + part[1][t64 * 2 + 1] + part[2][t64 * 2 + 1];
        float inv = (e > s) ? 1.0f / (float)(e - s) : 0.f;
        row[t64 * 2] = a0 * inv;
        row[t64 * 2 + 1] = a1 * inv;
    }
    __syncthreads();
    int t = threadIdx.x;
    if (t < 64) {
        float acc = bmu[t];
        for (int k = 0; k < 128; ++k) acc += row[k] * Wmu[k * 64 + t];
        mlv[t] = acc;
    } else if (t < 128) {
        int t2 = t - 64;
        float acc = blv[t2];
        for (int k = 0; k < 128; ++k) acc += row[k] * Wlv[k * 64 + t2];
        mlv[64 + t2] = acc;
    }
    __syncthreads();
    if (t < 64) {
        float mu = mlv[t], lv = mlv[64 + t];
        mu_o[g * 64 + t] = mu;
        lv_o[g * 64 + t] = lv;
        zr[t] = mu + eps[g * 64 + t] * expf(0.5f * lv);
    }
    __syncthreads();
    if (t < 128) {
        float acc = d1[t];
        for (int k = 0; k < 64; ++k) acc += zr[k] * D1[k * 128 + t];
        p1[t] = fmaxf(acc, 0.f);
    }
    __syncthreads();
    if (t < 128) {
        float acc = d2[t];
        for (int k = 0; k < 128; ++k) acc += p1[k] * D2[k * 128 + t];
        p2out[g * 128 + t] = (unsigned short)__half_as_ushort(__float2half(fmaxf(acc, 0.f)));
    }
}

// ---- probs = sigmoid(p2 @ D3 + d3) via MFMA f16; no LDS; 64x64 tiles ----
__global__ __launch_bounds__(256) void k_dec3m(const unsigned short* __restrict__ Ab,
        const unsigned short* __restrict__ Wt, const float* __restrict__ b,
        float* __restrict__ out) {
    int lane = threadIdx.x & 63;
    int w = threadIdx.x >> 6;
    int r0 = blockIdx.x * 64 + w * 16;          // m in 0..511
    int c0 = blockIdx.y * 64;                    // n in 0..8127
    int arow = r0 + (lane & 15);
    f16x8 af[4];
    #pragma unroll
    for (int ks = 0; ks < 4; ++ks) {
        union { bf16x8 r; f16x8 h; } ca;
        ca.r = *(const bf16x8*)&Ab[arow * 128 + ks * 32 + (lane >> 4) * 8];
        af[ks] = ca.h;
    }
    f32x4 acc[4];
    #pragma unroll
    for (int nt = 0; nt < 4; ++nt) acc[nt] = (f32x4){0.f, 0.f, 0.f, 0.f};
    #pragma unroll
    for (int nt = 0; nt < 4; ++nt) {
        long n = c0 + nt * 16 + (lane & 15);
        #pragma unroll
        for (int ks = 0; ks < 4; ++ks) {
            union { bf16x8 r; f16x8 h; } cb;
            cb.r = *(const bf16x8*)&Wt[n * 128 + ks * 32 + (lane >> 4) * 8];
            acc[nt] = __builtin_amdgcn_mfma_f32_16x16x32_f16(af[ks], cb.h, acc[nt], 0, 0, 0);
        }
    }
    #pragma unroll
    for (int nt = 0; nt < 4; ++nt) {
        int col = c0 + nt * 16 + (lane & 15);
        float bias = b[col];
        #pragma unroll
        for (int r = 0; r < 4; ++r) {
            int row = r0 + (lane >> 4) * 4 + r;
            float v = acc[nt][r] + bias;
            out[(long)row * OUTS + col] = 1.f / (1.f + expf(-v));
        }
    }
}

// ---- build symmetric adjacency ----
__global__ __launch_bounds__(256) void k_adj(const float* __restrict__ probs, float* __restrict__ adj) {
    int t = blockIdx.x * 256 + threadIdx.x;
    int g = t >> 12;
    int rem = t & 4095;
    int r = rem >> 5;
    int c0 = (rem & 31) * 4;
    const float* pg = &probs[g * OUTS];
    float4 o;
    float* op = (float*)&o;
    #pragma unroll
    for (int j = 0; j < 4; ++j) {
        int c = c0 + j;
        if (c == r) { op[j] = 0.f; continue; }
        int a = c < r ? c : r;
        int b = c < r ? r : c;
        int k = a * (255 - a) / 2 + (b - a - 1);
        op[j] = pg[k];
    }
    *(float4*)&adj[(long)t * 4] = o;
}

extern "C" void kernel_launch(void* const* d_in, const int* in_sizes, int n_in,
                              void* d_out, int out_size, void* d_ws, size_t ws_size,
                              hipStream_t stream) {
    const float* x   = (const float*)d_in[0];
    const int*   ei  = (const int*)d_in[1];
    const int* batch = (const int*)d_in[2];
    const float* eps = (const float*)d_in[3];
    const float* W1  = (const float*)d_in[4];
    const float* b1  = (const float*)d_in[5];
    const float* W2  = (const float*)d_in[6];
    const float* b2  = (const float*)d_in[7];
    const float* Wmu = (const float*)d_in[8];
    const float* bmu = (const float*)d_in[9];
    const float* Wlv = (const float*)d_in[10];
    const float* blv = (const float*)d_in[11];
    const float* D1  = (const float*)d_in[12];
    const float* d1  = (const float*)d_in[13];
    const float* D2  = (const float*)d_in[14];
    const float* d2  = (const float*)d_in[15];
    const float* D3  = (const float*)d_in[16];
    const float* d3  = (const float*)d_in[17];

    const int* esrc = ei;
    const int* edst = ei + NE;

    float* out  = (float*)d_out;
    float* mu_o = out + 8388608;
    float* lv_o = mu_o + 32768;

    // --- CSR + small scratch in d_out (region fully overwritten by k_adj at the end) ---
    int*   colidx   = (int*)out;                  // 1,600,000
    int*   cnti     = colidx + 1600000;           // 100,000
    int*   rowptr   = cnti + 100000;              // 100,000
    int*   seg_end  = rowptr + 100000;            // 512
    float* dinv     = (float*)(seg_end + 512);    // 100,000
    int*   scanhist = (int*)(dinv + 100000);      // 196*197 = 38,612
    int*   bucketbase = scanhist + 38612;         // 196
    unsigned short* wt3t = (unsigned short*)(bucketbase + 256);  // 1,040,384 u16

    // --- ws layout (float-unit offsets) ---
    float* ws = (float*)d_ws;
    unsigned* u1b = (unsigned*)ws;                         // 1.6M uints (fp8, 16/row)
    unsigned char* u2b = (unsigned char*)(ws + 6400000);   // 12.8M bytes (fp8)
    unsigned* h2b = (unsigned*)(ws + 16000000);            // 6.4M uints (bf16x2)
    unsigned short* wt1 = (unsigned short*)(ws + 22400000);   // 8192 u16 (f16)
    unsigned short* wt2 = wt1 + 8192;                         // 16384 u16 (bf16)
    int* tmp = (int*)(ws + 22420000);                      // 1.6M+ ints
    // decoder scratch aliases u1b (dead after gconv1)
    unsigned short* p2b = (unsigned short*)ws;             // 65,536 u16
    float* probs = ws + 65536;                             // 4.16M floats (u1b region, dead)

    // ---- CSR build + weight conversions (one launch), zero global atomics ----
    k_part<<<NPB + 48 + 1016, 512, 0, stream>>>(esrc, edst, tmp, scanhist,
                                                W1, W2, D3, wt1, wt2, wt3t);
    k_btotseg<<<392, 256, 0, stream>>>(scanhist, bucketbase, batch, seg_end);
    k_fill2<<<NB2, 1024, 0, stream>>>(bucketbase, scanhist, tmp, colidx, cnti, rowptr,
                                      dinv, x, u1b);

    // ---- fused conv1 (gather + f16 MFMA GEMM -> fp8) ----
    k_gconv1<<<1563, 256, 0, stream>>>(rowptr, cnti, colidx, u1b, dinv, wt1, b1, u2b);

    // ---- fused conv2 (gather + bf16 MFMA GEMM -> bf16) ----
    k_gconv2<<<1563, 256, 0, stream>>>(rowptr, cnti, colidx, (const unsigned*)u2b, dinv,
                                       wt2, b2, (unsigned short*)h2b);

    // ---- fused pool + decoder head ----
    k_pooldec<<<NG, 256, 0, stream>>>(h2b, seg_end, Wmu, bmu, Wlv, blv, eps,
                                      D1, d1, D2, d2, mu_o, lv_o, p2b);

    // ---- MFMA decoder output + adjacency ----
    dim3 g3(8, 127);
    k_dec3m<<<g3, 256, 0, stream>>>(p2b, wt3t, d3, probs);
    k_adj<<<8192, 256, 0, stream>>>(probs, out);
}

// Round 17
// 200.684 us; speedup vs baseline: 1.1484x; 1.1484x over previous
//
#include <hip/hip_runtime.h>
#include <hip/hip_fp16.h>

#define NN 100000
#define NE 1600000
#define NG 512
#define OUTS 8128
#define NB2 196     // coarse buckets of 512 nodes (196*512 = 100352 >= NN)
#define CHUNK 8192
#define NPB 196     // ceil(NE/CHUNK)

typedef short bf16x8 __attribute__((ext_vector_type(8)));
typedef _Float16 f16x8 __attribute__((ext_vector_type(8)));
typedef _Float16 f16x2 __attribute__((ext_vector_type(2)));
typedef float f32x4 __attribute__((ext_vector_type(4)));

__device__ __forceinline__ unsigned pack_bf16x2(float a, float b) {
    unsigned ua = __float_as_uint(a);
    unsigned ub = __float_as_uint(b);
    ua = (ua + 0x7fffu + ((ua >> 16) & 1u)) >> 16;
    ub = (ub + 0x7fffu + ((ub >> 16) & 1u)) >> 16;
    return ua | (ub << 16);
}
__device__ __forceinline__ unsigned short f2bf(float f) {
    unsigned u = __float_as_uint(f);
    u = (u + 0x7fffu + ((u >> 16) & 1u)) >> 16;
    return (unsigned short)u;
}
// f32 pair -> packed f16x2 (RTZ), as raw uint
__device__ __forceinline__ unsigned cvt_pkrtz_u(float a, float b) {
    auto h = __builtin_amdgcn_cvt_pkrtz(a, b);
    union { decltype(h) h2; unsigned u; } c; c.h2 = h; return c.u;
}
__device__ __forceinline__ f16x2 u2h(unsigned u) { union { unsigned u; f16x2 h; } c; c.u = u; return c.h; }

// e4m3 encode, f >= 0 (relu'd): e4m3(v) == f16(v/256) with 10->3 mantissa round
__device__ __forceinline__ unsigned f2fp8(float f) {
    unsigned h = (unsigned)__half_as_ushort(__float2half(f * 0.00390625f));
    return (h + 0x3Fu + ((h >> 7) & 1u)) >> 7;
}
// e4m3 encode, signed
__device__ __forceinline__ unsigned f2fp8s(float f) {
    unsigned h = (unsigned)__half_as_ushort(__float2half(f * 0.00390625f));
    unsigned s = (h >> 8) & 0x80u;
    unsigned mag = h & 0x7fffu;
    return s | ((mag + 0x3Fu + ((mag >> 7) & 1u)) >> 7);
}

// unsigned packed decode (relu'd data): 4 fp8 -> two f16x2 accumulators
#define DECO(W, LO, HI) { LO += u2h(((W) & 0x007f007fu) << 7); HI += u2h(((W) & 0x7f007f00u) >> 1); }
// signed packed decode
#define DECOS(W, LO, HI) { \
    LO += u2h((((W) & 0x007f007fu) << 7) | (((W) & 0x00800080u) << 8)); \
    HI += u2h((((W) & 0x7f007f00u) >> 1) | ((W) & 0x80008000u)); }

// ---- phase 1 + weight conversions in one launch ----
__global__ __launch_bounds__(512) void k_part(const int* __restrict__ src, const int* __restrict__ dst,
        int* __restrict__ tmp, int* __restrict__ scanhist,
        const float* __restrict__ W1, const float* __restrict__ W2, const float* __restrict__ D3,
        unsigned short* __restrict__ wt1, unsigned short* __restrict__ wt2,
        unsigned short* __restrict__ wt3t) {
    int t = threadIdx.x;
    if (blockIdx.x >= NPB) {
        int blk2 = blockIdx.x - NPB;
        if (blk2 < 48) {
            int i = blk2 * 512 + t;
            if (i < 8192) {                      // wt1: [128][64] f16, transposed
                int n = i >> 6, k = i & 63;
                wt1[i] = (unsigned short)__half_as_ushort(__float2half(W1[k * 128 + n]));
            } else {                             // wt2: [128][128] bf16, transposed
                int e = i - 8192;
                int n = e >> 7, k = e & 127;
                wt2[e] = f2bf(W2[k * 128 + n]);
            }
        } else {
            __shared__ float tile[32][33];
            int bb = blk2 - 48;                  // 0..1015
            int n0 = (bb % 254) * 32, k0 = (bb / 254) * 32;
            for (int i = t; i < 1024; i += 512) {
                int kk = i >> 5, nn = i & 31;
                tile[kk][nn] = D3[(long)(k0 + kk) * OUTS + n0 + nn];
            }
            __syncthreads();
            for (int i = t; i < 1024; i += 512) {
                int nn = i >> 5, kk = i & 31;
                wt3t[(long)(n0 + nn) * 128 + k0 + kk] =
                    (unsigned short)__half_as_ushort(__float2half(tile[kk][nn]));
            }
        }
        return;
    }
    __shared__ int hist[NB2], cur[NB2], scan[256];
    int p = blockIdx.x;
    int e0 = p * CHUNK;
    int e1 = min(e0 + CHUNK, NE);
    for (int i = t; i < NB2; i += 512) hist[i] = 0;
    __syncthreads();
    for (int e = e0 + t; e < e1; e += 512)
        atomicAdd(&hist[dst[e] >> 9], 1);
    __syncthreads();
    int h = 0;
    if (t < 256) { h = (t < NB2) ? hist[t] : 0; scan[t] = h; }
    __syncthreads();
    for (int off = 1; off < 256; off <<= 1) {
        int v = (t < 256 && t >= off) ? scan[t - off] : 0;
        __syncthreads();
        if (t < 256) scan[t] += v;
        __syncthreads();
    }
    if (t < NB2) {
        int excl = scan[t] - h;
        cur[t] = excl;
        scanhist[p * (NB2 + 1) + t] = excl;
    }
    if (t == 0) scanhist[p * (NB2 + 1) + NB2] = e1 - e0;
    __syncthreads();
    for (int e = e0 + t; e < e1; e += 512) {
        int d = dst[e];
        int b = d >> 9;
        int r = atomicAdd(&cur[b], 1);          // LDS atomic only
        tmp[e0 + r] = (src[e] << 9) | (d & 511);
    }
}

// ---- block 0: bucket totals + scan -> bucketbase; blocks 1..: segment ends ----
__global__ __launch_bounds__(256) void k_btotseg(const int* __restrict__ scanhist,
        int* __restrict__ bucketbase, const int* __restrict__ batch, int* __restrict__ seg_end) {
    if (blockIdx.x == 0) {
        __shared__ int sc[256];
        int b = threadIdx.x;
        int tot = 0;
        if (b < NB2) {
            for (int p = 0; p < NPB; ++p)
                tot += scanhist[p * (NB2 + 1) + b + 1] - scanhist[p * (NB2 + 1) + b];
        }
        sc[b] = tot;
        __syncthreads();
        for (int off = 1; off < 256; off <<= 1) {
            int v = (b >= off) ? sc[b - off] : 0;
            __syncthreads();
            sc[b] += v;
            __syncthreads();
        }
        if (b < NB2) bucketbase[b] = sc[b] - tot;
    } else {
        int i = (blockIdx.x - 1) * 256 + threadIdx.x;
        if (i >= NN) return;
        int b = batch[i];
        int bn = (i == NN - 1) ? NG : batch[i + 1];
        for (int g = b; g < bn; ++g) seg_end[g] = i + 1;
        if (i == 0) {
            for (int g = 0; g < b; ++g) seg_end[g] = 0;
        }
    }
}

// ---- phase 2: per-bucket count+scan+place; emits cnti/rowptr/dinv/colidx AND u1b = fp8(x*dinv) ----
__global__ __launch_bounds__(1024) void k_fill2(const int* __restrict__ bucketbase,
        const int* __restrict__ scanhist, const int* __restrict__ tmp,
        int* __restrict__ colidx, int* __restrict__ cnti, int* __restrict__ rowptr,
        float* __restrict__ dinv, const float* __restrict__ x, unsigned* __restrict__ u1b) {
    __shared__ int lc[512], rb[512], sc[256];
    __shared__ float ldv[512];
    int b = blockIdx.x, t = threadIdx.x;
    int n0 = b << 9;
    if (t < 512) lc[t] = 0;
    __syncthreads();
    int w = t >> 6, lane = t & 63;              // w in 0..15
    for (int p = w; p < NPB; p += 16) {
        int s0 = scanhist[p * (NB2 + 1) + b];
        int s1 = scanhist[p * (NB2 + 1) + b + 1];
        int base = p * CHUNK;
        for (int i = s0 + lane; i < s1; i += 64)
            atomicAdd(&lc[tmp[base + i] & 511], 1);
    }
    __syncthreads();
    int v0 = 0, v1 = 0, s = 0;
    if (t < 256) { v0 = lc[2 * t]; v1 = lc[2 * t + 1]; s = v0 + v1; sc[t] = s; }
    __syncthreads();
    for (int off = 1; off < 256; off <<= 1) {
        int xv = (t < 256 && t >= off) ? sc[t - off] : 0;
        __syncthreads();
        if (t < 256) sc[t] += xv;
        __syncthreads();
    }
    if (t < 256) {
        int excl = sc[t] - s;
        int base0 = bucketbase[b];
        rb[2 * t] = base0 + excl;
        rb[2 * t + 1] = base0 + excl + v0;
        float dv0 = rsqrtf((float)v0 + 1.0f);
        float dv1 = rsqrtf((float)v1 + 1.0f);
        ldv[2 * t] = dv0;
        ldv[2 * t + 1] = dv1;
        int node0 = n0 + 2 * t;
        if (node0 < NN) {
            cnti[node0] = v0;
            rowptr[node0] = base0 + excl;
            dinv[node0] = dv0;
        }
        if (node0 + 1 < NN) {
            cnti[node0 + 1] = v1;
            rowptr[node0 + 1] = base0 + excl + v0;
            dinv[node0 + 1] = dv1;
        }
    }
    __syncthreads();
    if (t < 512) lc[t] = 0;
    __syncthreads();
    for (int p = w; p < NPB; p += 16) {
        int s0 = scanhist[p * (NB2 + 1) + b];
        int s1 = scanhist[p * (NB2 + 1) + b + 1];
        int base = p * CHUNK;
        for (int i = s0 + lane; i < s1; i += 64) {
            int v = tmp[base + i];
            int dl = v & 511;
            int pos = atomicAdd(&lc[dl], 1);    // LDS atomic only
            colidx[rb[dl] + pos] = v >> 9;
        }
    }
    // x-scale phase: u1b[node][c] = fp8s(x*dinv), 16 uints (64ch) per node
    for (int i = t; i < 512 * 16; i += 1024) {
        int local = i >> 4, c = i & 15;
        int node = n0 + local;
        if (node >= NN) continue;
        float4 xv = *(const float4*)&x[(long)node * 64 + c * 4];
        float d = ldv[local];
        unsigned o = f2fp8s(xv.x * d) | (f2fp8s(xv.y * d) << 8)
                   | (f2fp8s(xv.z * d) << 16) | (f2fp8s(xv.w * d) << 24);
        u1b[node * 16 + c] = o;
    }
}

// ---- gather1: s1 = f16(dinv_n * (u1[n] + sum u1[src])), 64ch signed fp8 in ----
// 4 lanes/node, uint4 (16ch) per lane, 8-deep unroll (128B in flight/lane)
__global__ __launch_bounds__(256) void k_gather1(const int* __restrict__ rowptr,
        const int* __restrict__ cnti, const int* __restrict__ colidx,
        const unsigned* __restrict__ u, const float* __restrict__ dinv,
        unsigned* __restrict__ s1) {
    int node = blockIdx.x * 64 + (threadIdx.x >> 2);
    if (node >= NN) return;
    int lane = threadIdx.x & 3;
    const uint4* uf = (const uint4*)u;          // row = 4 uint4 (64 fp8)
    uint4 self = uf[node * 4 + lane];
    f16x2 z = {(_Float16)0.f, (_Float16)0.f};
    f16x2 la0 = z, ha0 = z, la1 = z, ha1 = z, la2 = z, ha2 = z, la3 = z, ha3 = z;
    f16x2 lb0 = z, hb0 = z, lb1 = z, hb1 = z, lb2 = z, hb2 = z, lb3 = z, hb3 = z;
    DECOS(self.x, la0, ha0) DECOS(self.y, la1, ha1) DECOS(self.z, la2, ha2) DECOS(self.w, la3, ha3)
    int n = cnti[node];
    const int* ci = colidx + rowptr[node];
    int j = 0;
    for (; j + 8 <= n; j += 8) {
        uint4 v0 = uf[ci[j] * 4 + lane];
        uint4 v1 = uf[ci[j + 1] * 4 + lane];
        uint4 v2 = uf[ci[j + 2] * 4 + lane];
        uint4 v3 = uf[ci[j + 3] * 4 + lane];
        uint4 v4 = uf[ci[j + 4] * 4 + lane];
        uint4 v5 = uf[ci[j + 5] * 4 + lane];
        uint4 v6 = uf[ci[j + 6] * 4 + lane];
        uint4 v7 = uf[ci[j + 7] * 4 + lane];
        DECOS(v0.x, la0, ha0) DECOS(v0.y, la1, ha1) DECOS(v0.z, la2, ha2) DECOS(v0.w, la3, ha3)
        DECOS(v1.x, lb0, hb0) DECOS(v1.y, lb1, hb1) DECOS(v1.z, lb2, hb2) DECOS(v1.w, lb3, hb3)
        DECOS(v2.x, la0, ha0) DECOS(v2.y, la1, ha1) DECOS(v2.z, la2, ha2) DECOS(v2.w, la3, ha3)
        DECOS(v3.x, lb0, hb0) DECOS(v3.y, lb1, hb1) DECOS(v3.z, lb2, hb2) DECOS(v3.w, lb3, hb3)
        DECOS(v4.x, la0, ha0) DECOS(v4.y, la1, ha1) DECOS(v4.z, la2, ha2) DECOS(v4.w, la3, ha3)
        DECOS(v5.x, lb0, hb0) DECOS(v5.y, lb1, hb1) DECOS(v5.z, lb2, hb2) DECOS(v5.w, lb3, hb3)
        DECOS(v6.x, la0, ha0) DECOS(v6.y, la1, ha1) DECOS(v6.z, la2, ha2) DECOS(v6.w, la3, ha3)
        DECOS(v7.x, lb0, hb0) DECOS(v7.y, lb1, hb1) DECOS(v7.z, lb2, hb2) DECOS(v7.w, lb3, hb3)
    }
    if (j + 4 <= n) {
        uint4 v0 = uf[ci[j] * 4 + lane];
        uint4 v1 = uf[ci[j + 1] * 4 + lane];
        uint4 v2 = uf[ci[j + 2] * 4 + lane];
        uint4 v3 = uf[ci[j + 3] * 4 + lane];
        DECOS(v0.x, la0, ha0) DECOS(v0.y, la1, ha1) DECOS(v0.z, la2, ha2) DECOS(v0.w, la3, ha3)
        DECOS(v1.x, lb0, hb0) DECOS(v1.y, lb1, hb1) DECOS(v1.z, lb2, hb2) DECOS(v1.w, lb3, hb3)
        DECOS(v2.x, la0, ha0) DECOS(v2.y, la1, ha1) DECOS(v2.z, la2, ha2) DECOS(v2.w, la3, ha3)
        DECOS(v3.x, lb0, hb0) DECOS(v3.y, lb1, hb1) DECOS(v3.z, lb2, hb2) DECOS(v3.w, lb3, hb3)
        j += 4;
    }
    for (; j < n; ++j) {
        uint4 va = uf[ci[j] * 4 + lane];
        DECOS(va.x, la0, ha0) DECOS(va.y, la1, ha1) DECOS(va.z, la2, ha2) DECOS(va.w, la3, ha3)
    }
    la0 += lb0; ha0 += hb0; la1 += lb1; ha1 += hb1;
    la2 += lb2; ha2 += hb2; la3 += lb3; ha3 += hb3;
    float d = dinv[node] * 256.0f;              // *256 decode scale
    uint4 o1, o2;
    o1.x = cvt_pkrtz_u((float)la0[0] * d, (float)ha0[0] * d);
    o1.y = cvt_pkrtz_u((float)la0[1] * d, (float)ha0[1] * d);
    o1.z = cvt_pkrtz_u((float)la1[0] * d, (float)ha1[0] * d);
    o1.w = cvt_pkrtz_u((float)la1[1] * d, (float)ha1[1] * d);
    o2.x = cvt_pkrtz_u((float)la2[0] * d, (float)ha2[0] * d);
    o2.y = cvt_pkrtz_u((float)la2[1] * d, (float)ha2[1] * d);
    o2.z = cvt_pkrtz_u((float)la3[0] * d, (float)ha3[0] * d);
    o2.w = cvt_pkrtz_u((float)la3[1] * d, (float)ha3[1] * d);
    *(uint4*)&s1[node * 32 + lane * 8] = o1;
    *(uint4*)&s1[node * 32 + lane * 8 + 4] = o2;
}

// ---- gather2: s2 = bf16(16*dinv_n * sum fp8rows), 128ch fp8 (relu'd, unsigned) ----
// 8 lanes/node, uint4 (16ch) per lane, 8-deep unroll
__global__ __launch_bounds__(256) void k_gather2(const int* __restrict__ rowptr,
        const int* __restrict__ cnti, const int* __restrict__ colidx,
        const unsigned* __restrict__ u, const float* __restrict__ dinv,
        unsigned* __restrict__ s2) {
    int node = blockIdx.x * 32 + (threadIdx.x >> 3);
    int lane = threadIdx.x & 7;
    const uint4* uf = (const uint4*)u;          // row = 8 uint4 (128 fp8)
    uint4 self = uf[node * 8 + lane];
    f16x2 z = {(_Float16)0.f, (_Float16)0.f};
    f16x2 la0 = z, ha0 = z, la1 = z, ha1 = z, la2 = z, ha2 = z, la3 = z, ha3 = z;
    f16x2 lb0 = z, hb0 = z, lb1 = z, hb1 = z, lb2 = z, hb2 = z, lb3 = z, hb3 = z;
    DECO(self.x, la0, ha0) DECO(self.y, la1, ha1) DECO(self.z, la2, ha2) DECO(self.w, la3, ha3)
    int n = cnti[node];
    const int* ci = colidx + rowptr[node];
    int j = 0;
    for (; j + 8 <= n; j += 8) {
        uint4 v0 = uf[ci[j] * 8 + lane];
        uint4 v1 = uf[ci[j + 1] * 8 + lane];
        uint4 v2 = uf[ci[j + 2] * 8 + lane];
        uint4 v3 = uf[ci[j + 3] * 8 + lane];
        uint4 v4 = uf[ci[j + 4] * 8 + lane];
        uint4 v5 = uf[ci[j + 5] * 8 + lane];
        uint4 v6 = uf[ci[j + 6] * 8 + lane];
        uint4 v7 = uf[ci[j + 7] * 8 + lane];
        DECO(v0.x, la0, ha0) DECO(v0.y, la1, ha1) DECO(v0.z, la2, ha2) DECO(v0.w, la3, ha3)
        DECO(v1.x, lb0, hb0) DECO(v1.y, lb1, hb1) DECO(v1.z, lb2, hb2) DECO(v1.w, lb3, hb3)
        DECO(v2.x, la0, ha0) DECO(v2.y, la1, ha1) DECO(v2.z, la2, ha2) DECO(v2.w, la3, ha3)
        DECO(v3.x, lb0, hb0) DECO(v3.y, lb1, hb1) DECO(v3.z, lb2, hb2) DECO(v3.w, lb3, hb3)
        DECO(v4.x, la0, ha0) DECO(v4.y, la1, ha1) DECO(v4.z, la2, ha2) DECO(v4.w, la3, ha3)
        DECO(v5.x, lb0, hb0) DECO(v5.y, lb1, hb1) DECO(v5.z, lb2, hb2) DECO(v5.w, lb3, hb3)
        DECO(v6.x, la0, ha0) DECO(v6.y, la1, ha1) DECO(v6.z, la2, ha2) DECO(v6.w, la3, ha3)
        DECO(v7.x, lb0, hb0) DECO(v7.y, lb1, hb1) DECO(v7.z, lb2, hb2) DECO(v7.w, lb3, hb3)
    }
    if (j + 4 <= n) {
        uint4 v0 = uf[ci[j] * 8 + lane];
        uint4 v1 = uf[ci[j + 1] * 8 + lane];
        uint4 v2 = uf[ci[j + 2] * 8 + lane];
        uint4 v3 = uf[ci[j + 3] * 8 + lane];
        DECO(v0.x, la0, ha0) DECO(v0.y, la1, ha1) DECO(v0.z, la2, ha2) DECO(v0.w, la3, ha3)
        DECO(v1.x, lb0, hb0) DECO(v1.y, lb1, hb1) DECO(v1.z, lb2, hb2) DECO(v1.w, lb3, hb3)
        DECO(v2.x, la0, ha0) DECO(v2.y, la1, ha1) DECO(v2.z, la2, ha2) DECO(v2.w, la3, ha3)
        DECO(v3.x, lb0, hb0) DECO(v3.y, lb1, hb1) DECO(v3.z, lb2, hb2) DECO(v3.w, lb3, hb3)
        j += 4;
    }
    for (; j < n; ++j) {
        uint4 va = uf[ci[j] * 8 + lane];
        DECO(va.x, la0, ha0) DECO(va.y, la1, ha1) DECO(va.z, la2, ha2) DECO(va.w, la3, ha3)
    }
    la0 += lb0; ha0 += hb0; la1 += lb1; ha1 += hb1;
    la2 += lb2; ha2 += hb2; la3 += lb3; ha3 += hb3;
    float d = dinv[node] * 16.0f;   // *256 (decode) / 16 (encode scale)
    uint4 o1, o2;
    o1.x = pack_bf16x2((float)la0[0] * d, (float)ha0[0] * d);
    o1.y = pack_bf16x2((float)la0[1] * d, (float)ha0[1] * d);
    o1.z = pack_bf16x2((float)la1[0] * d, (float)ha1[0] * d);
    o1.w = pack_bf16x2((float)la1[1] * d, (float)ha1[1] * d);
    o2.x = pack_bf16x2((float)la2[0] * d, (float)ha2[0] * d);
    o2.y = pack_bf16x2((float)la2[1] * d, (float)ha2[1] * d);
    o2.z = pack_bf16x2((float)la3[0] * d, (float)ha3[0] * d);
    o2.w = pack_bf16x2((float)la3[1] * d, (float)ha3[1] * d);
    *(uint4*)&s2[node * 64 + lane * 8] = o1;
    *(uint4*)&s2[node * 64 + lane * 8 + 4] = o2;
}

// ---- MFMA GEMM: h = relu(A@W + bias); AF16: f16 inputs; EPI 0: out fp8(16*dinv*h); 1: bf16 ----
template<int K, int EPI, int AF16>
__global__ __launch_bounds__(256) void k_gemm_mfma(const unsigned short* __restrict__ Ab,
        const unsigned short* __restrict__ wt, const float* __restrict__ dinv,
        const float* __restrict__ bias, void* __restrict__ outp) {
    constexpr int KS = K / 32;
    constexpr int SLOTS = K / 8;
    __shared__ __align__(16) unsigned short wlds[128 * K];
    char* lb = (char*)wlds;
    for (int c = threadIdx.x; c < 128 * SLOTS; c += 256) {
        int n = c / SLOTS, s = c - n * SLOTS;
        *(uint4*)(lb + n * (2 * K) + ((s ^ (n & 7)) << 4)) = *(const uint4*)(wt + c * 8);
    }
    __syncthreads();
    int lane = threadIdx.x & 63;
    int w = threadIdx.x >> 6;
    int r0 = blockIdx.x * 64 + w * 16;
    int arow = r0 + (lane & 15);
    if (arow >= NN) arow = NN - 1;
    bf16x8 af[KS];
    #pragma unroll
    for (int ks = 0; ks < KS; ++ks)
        af[ks] = *(const bf16x8*)&Ab[(long)arow * K + ks * 32 + (lane >> 4) * 8];
    f32x4 acc[8];
    #pragma unroll
    for (int t = 0; t < 8; ++t) acc[t] = (f32x4){0.f, 0.f, 0.f, 0.f};
    #pragma unroll
    for (int ks = 0; ks < KS; ++ks) {
        #pragma unroll
        for (int t = 0; t < 8; ++t) {
            int n = t * 16 + (lane & 15);
            int slot = ks * 4 + (lane >> 4);
            bf16x8 braw = *(const bf16x8*)(lb + n * (2 * K) + ((slot ^ (n & 7)) << 4));
            if constexpr (AF16) {
                union { bf16x8 r; f16x8 h; } ca, cb;
                ca.r = af[ks]; cb.r = braw;
                acc[t] = __builtin_amdgcn_mfma_f32_16x16x32_f16(ca.h, cb.h, acc[t], 0, 0, 0);
            } else {
                acc[t] = __builtin_amdgcn_mfma_f32_16x16x32_bf16(af[ks], braw, acc[t], 0, 0, 0);
            }
        }
    }
    float bv[8];
    #pragma unroll
    for (int t = 0; t < 8; ++t) bv[t] = bias[t * 16 + (lane & 15)];
    #pragma unroll
    for (int r = 0; r < 4; ++r) {
        long row = r0 + (lane >> 4) * 4 + r;
        if (row >= NN) continue;
        float d = dinv[row];
        #pragma unroll
        for (int t = 0; t < 8; ++t) {
            float val = fmaxf(acc[t][r] + bv[t], 0.f);
            int col = t * 16 + (lane & 15);
            if (EPI == 0)
                ((unsigned char*)outp)[row * 128 + col] = (unsigned char)f2fp8(val * (16.0f * d));
            else
                ((unsigned short*)outp)[row * 128 + col] = f2bf(val);
        }
    }
}

// ---- fused: segmented mean pool + mu/lv/z + 2 MLP layers; one block (256 thr) per graph ----
__global__ __launch_bounds__(256) void k_pooldec(const unsigned* __restrict__ h,
        const int* __restrict__ seg_end,
        const float* __restrict__ Wmu, const float* __restrict__ bmu,
        const float* __restrict__ Wlv, const float* __restrict__ blv,
        const float* __restrict__ eps,
        const float* __restrict__ D1, const float* __restrict__ d1,
        const float* __restrict__ D2, const float* __restrict__ d2,
        float* __restrict__ mu_o, float* __restrict__ lv_o,
        unsigned short* __restrict__ p2out) {
    __shared__ float part[3][128];
    __shared__ float row[128], mlv[128], zr[64], p1[128];
    int g = blockIdx.x;
    int w = threadIdx.x >> 6, t64 = threadIdx.x & 63;
    int s = (g == 0) ? 0 : seg_end[g - 1];
    int e = seg_end[g];
    float a0 = 0.f, a1 = 0.f;
    for (int i = s + w; i < e; i += 4) {
        unsigned u = h[(long)i * 64 + t64];
        a0 += __uint_as_float(u << 16);
        a1 += __uint_as_float(u & 0xffff0000u);
    }
    if (w) { part[w - 1][t64 * 2] = a0; part[w - 1][t64 * 2 + 1] = a1; }
    __syncthreads();
    if (w == 0) {
        a0 += part[0][t64 * 2] + part[1][t64 * 2] + part[2][t64 * 2];
        a1 += part[0][t64 * 2 + 1] + part[1][t64 * 2 + 1] + part[2][t64 * 2 + 1];
        float inv = (e > s) ? 1.0f / (float)(e - s) : 0.f;
        row[t64 * 2] = a0 * inv;
        row[t64 * 2 + 1] = a1 * inv;
    }
    __syncthreads();
    int t = threadIdx.x;
    if (t < 64) {
        float acc = bmu[t];
        for (int k = 0; k < 128; ++k) acc += row[k] * Wmu[k * 64 + t];
        mlv[t] = acc;
    } else if (t < 128) {
        int t2 = t - 64;
        float acc = blv[t2];
        for (int k = 0; k < 128; ++k) acc += row[k] * Wlv[k * 64 + t2];
        mlv[64 + t2] = acc;
    }
    __syncthreads();
    if (t < 64) {
        float mu = mlv[t], lv = mlv[64 + t];
        mu_o[g * 64 + t] = mu;
        lv_o[g * 64 + t] = lv;
        zr[t] = mu + eps[g * 64 + t] * expf(0.5f * lv);
    }
    __syncthreads();
    if (t < 128) {
        float acc = d1[t];
        for (int k = 0; k < 64; ++k) acc += zr[k] * D1[k * 128 + t];
        p1[t] = fmaxf(acc, 0.f);
    }
    __syncthreads();
    if (t < 128) {
        float acc = d2[t];
        for (int k = 0; k < 128; ++k) acc += p1[k] * D2[k * 128 + t];
        p2out[g * 128 + t] = (unsigned short)__half_as_ushort(__float2half(fmaxf(acc, 0.f)));
    }
}

// ---- probs = sigmoid(p2 @ D3 + d3) via MFMA f16; no LDS; 64x64 tiles ----
__global__ __launch_bounds__(256) void k_dec3m(const unsigned short* __restrict__ Ab,
        const unsigned short* __restrict__ Wt, const float* __restrict__ b,
        float* __restrict__ out) {
    int lane = threadIdx.x & 63;
    int w = threadIdx.x >> 6;
    int r0 = blockIdx.x * 64 + w * 16;          // m in 0..511
    int c0 = blockIdx.y * 64;                    // n in 0..8127
    int arow = r0 + (lane & 15);
    f16x8 af[4];
    #pragma unroll
    for (int ks = 0; ks < 4; ++ks) {
        union { bf16x8 r; f16x8 h; } ca;
        ca.r = *(const bf16x8*)&Ab[arow * 128 + ks * 32 + (lane >> 4) * 8];
        af[ks] = ca.h;
    }
    f32x4 acc[4];
    #pragma unroll
    for (int nt = 0; nt < 4; ++nt) acc[nt] = (f32x4){0.f, 0.f, 0.f, 0.f};
    #pragma unroll
    for (int nt = 0; nt < 4; ++nt) {
        long n = c0 + nt * 16 + (lane & 15);
        #pragma unroll
        for (int ks = 0; ks < 4; ++ks) {
            union { bf16x8 r; f16x8 h; } cb;
            cb.r = *(const bf16x8*)&Wt[n * 128 + ks * 32 + (lane >> 4) * 8];
            acc[nt] = __builtin_amdgcn_mfma_f32_16x16x32_f16(af[ks], cb.h, acc[nt], 0, 0, 0);
        }
    }
    #pragma unroll
    for (int nt = 0; nt < 4; ++nt) {
        int col = c0 + nt * 16 + (lane & 15);
        float bias = b[col];
        #pragma unroll
        for (int r = 0; r < 4; ++r) {
            int row = r0 + (lane >> 4) * 4 + r;
            float v = acc[nt][r] + bias;
            out[(long)row * OUTS + col] = 1.f / (1.f + expf(-v));
        }
    }
}

// ---- build symmetric adjacency ----
__global__ __launch_bounds__(256) void k_adj(const float* __restrict__ probs, float* __restrict__ adj) {
    int t = blockIdx.x * 256 + threadIdx.x;
    int g = t >> 12;
    int rem = t & 4095;
    int r = rem >> 5;
    int c0 = (rem & 31) * 4;
    const float* pg = &probs[g * OUTS];
    float4 o;
    float* op = (float*)&o;
    #pragma unroll
    for (int j = 0; j < 4; ++j) {
        int c = c0 + j;
        if (c == r) { op[j] = 0.f; continue; }
        int a = c < r ? c : r;
        int b = c < r ? r : c;
        int k = a * (255 - a) / 2 + (b - a - 1);
        op[j] = pg[k];
    }
    *(float4*)&adj[(long)t * 4] = o;
}

extern "C" void kernel_launch(void* const* d_in, const int* in_sizes, int n_in,
                              void* d_out, int out_size, void* d_ws, size_t ws_size,
                              hipStream_t stream) {
    const float* x   = (const float*)d_in[0];
    const int*   ei  = (const int*)d_in[1];
    const int* batch = (const int*)d_in[2];
    const float* eps = (const float*)d_in[3];
    const float* W1  = (const float*)d_in[4];
    const float* b1  = (const float*)d_in[5];
    const float* W2  = (const float*)d_in[6];
    const float* b2  = (const float*)d_in[7];
    const float* Wmu = (const float*)d_in[8];
    const float* bmu = (const float*)d_in[9];
    const float* Wlv = (const float*)d_in[10];
    const float* blv = (const float*)d_in[11];
    const float* D1  = (const float*)d_in[12];
    const float* d1  = (const float*)d_in[13];
    const float* D2  = (const float*)d_in[14];
    const float* d2  = (const float*)d_in[15];
    const float* D3  = (const float*)d_in[16];
    const float* d3  = (const float*)d_in[17];

    const int* esrc = ei;
    const int* edst = ei + NE;

    float* out  = (float*)d_out;
    float* mu_o = out + 8388608;
    float* lv_o = mu_o + 32768;

    // --- CSR + small scratch in d_out (region fully overwritten by k_adj at the end) ---
    int*   colidx   = (int*)out;                  // 1,600,000
    int*   cnti     = colidx + 1600000;           // 100,000
    int*   rowptr   = cnti + 100000;              // 100,000
    int*   seg_end  = rowptr + 100000;            // 512
    float* dinv     = (float*)(seg_end + 512);    // 100,000
    int*   scanhist = (int*)(dinv + 100000);      // 196*197 = 38,612
    int*   bucketbase = scanhist + 38612;         // 196
    unsigned short* wt3t = (unsigned short*)(bucketbase + 256);  // 1,040,384 u16

    // --- ws layout (float-unit offsets) ---
    float* ws = (float*)d_ws;
    unsigned* u1b = (unsigned*)ws;                         // 1.6M uints (fp8, 16/row)
    unsigned* s1u = (unsigned*)(ws + 3200000);             // 3.2M uints (f16x2)
    unsigned char* u2b = (unsigned char*)(ws + 6400000);   // 12.8M bytes (fp8)
    unsigned* s2u = (unsigned*)(ws + 9600000);             // 6.4M uints (bf16x2)
    unsigned* h2b = (unsigned*)(ws + 16000000);            // 6.4M uints (bf16x2)
    unsigned short* wt1 = (unsigned short*)(ws + 22400000);   // 8192 u16 (f16)
    unsigned short* wt2 = wt1 + 8192;                         // 16384 u16 (bf16)
    int* tmp = (int*)(ws + 22420000);                      // 1.6M+ ints
    // decoder scratch aliases u1b/s1u (dead by then)
    unsigned short* p2b = (unsigned short*)ws;             // 65,536 u16
    float* probs = ws + 65536;                             // 4.16M floats (s1u dead by then)

    // ---- CSR build + weight conversions (one launch), zero global atomics ----
    k_part<<<NPB + 48 + 1016, 512, 0, stream>>>(esrc, edst, tmp, scanhist,
                                                W1, W2, D3, wt1, wt2, wt3t);
    k_btotseg<<<392, 256, 0, stream>>>(scanhist, bucketbase, batch, seg_end);
    k_fill2<<<NB2, 1024, 0, stream>>>(bucketbase, scanhist, tmp, colidx, cnti, rowptr,
                                      dinv, x, u1b);

    // ---- conv1 (signed-fp8 gather in 64-ch x-space, then f16 MFMA GEMM -> fp8) ----
    k_gather1<<<1563, 256, 0, stream>>>(rowptr, cnti, colidx, u1b, dinv, s1u);
    k_gemm_mfma<64, 0, 1><<<1563, 256, 0, stream>>>((const unsigned short*)s1u, wt1, dinv, b1, u2b);

    // ---- conv2 (fp8 packed-decode gather, then bf16 MFMA GEMM) ----
    k_gather2<<<3125, 256, 0, stream>>>(rowptr, cnti, colidx, (const unsigned*)u2b, dinv, s2u);
    k_gemm_mfma<128, 1, 0><<<1563, 256, 0, stream>>>((const unsigned short*)s2u, wt2, dinv, b2, h2b);

    // ---- fused pool + decoder head ----
    k_pooldec<<<NG, 256, 0, stream>>>(h2b, seg_end, Wmu, bmu, Wlv, blv, eps,
                                      D1, d1, D2, d2, mu_o, lv_o, p2b);

    // ---- MFMA decoder output + adjacency ----
    dim3 g3(8, 127);
    k_dec3m<<<g3, 256, 0, stream>>>(p2b, wt3t, d3, probs);
    k_adj<<<8192, 256, 0, stream>>>(probs, out);
}